// Round 1
// baseline (1499.163 us; speedup 1.0000x reference)
//
#include <hip/hip_runtime.h>

#define N_NODES 100000
#define N_EDGES 1600000
#define D 128
#define BN_EPS 1e-5f

// ---------------- CSR build ----------------

__global__ __launch_bounds__(256) void k_deg(const int* __restrict__ dst, int* __restrict__ degi) {
    int e = blockIdx.x * 256 + threadIdx.x;
    if (e < N_EDGES) atomicAdd(&degi[dst[e]], 1);
}

__global__ __launch_bounds__(1024) void k_scan(const int* __restrict__ degi, int* __restrict__ rowptr,
                                               float* __restrict__ inv_deg) {
    __shared__ int sm[1024];
    const int t = threadIdx.x;
    const int CH = (N_NODES + 1023) / 1024;  // 98
    int base = t * CH;
    int s = 0;
    for (int i = 0; i < CH; i++) {
        int idx = base + i;
        if (idx < N_NODES) s += degi[idx];
    }
    sm[t] = s;
    __syncthreads();
    for (int off = 1; off < 1024; off <<= 1) {
        int v = 0;
        if (t >= off) v = sm[t - off];
        __syncthreads();
        if (t >= off) sm[t] += v;
        __syncthreads();
    }
    int run = (t == 0) ? 0 : sm[t - 1];
    for (int i = 0; i < CH; i++) {
        int idx = base + i;
        if (idx < N_NODES) {
            int d = degi[idx];
            rowptr[idx] = run;
            run += d;
            inv_deg[idx] = 1.0f / fmaxf((float)d, 1.0f);
        }
    }
    if (t == 1023) rowptr[N_NODES] = run;
}

__global__ __launch_bounds__(256) void k_fill(const int* __restrict__ src, const int* __restrict__ dst,
                                              const int* __restrict__ rowptr, int* __restrict__ cursor,
                                              int* __restrict__ colidx) {
    int e = blockIdx.x * 256 + threadIdx.x;
    if (e < N_EDGES) {
        int d = dst[e];
        int pos = atomicAdd(&cursor[d], 1);
        colidx[rowptr[d] + pos] = src[e];
    }
}

// ---------------- per-layer kernels ----------------

// mean aggregation: one block per node, one thread per channel
__global__ __launch_bounds__(128) void k_agg(const float* __restrict__ x, const int* __restrict__ rowptr,
                                             const int* __restrict__ colidx, const float* __restrict__ inv_deg,
                                             float* __restrict__ agg) {
    int n = blockIdx.x;
    int c = threadIdx.x;
    int b = rowptr[n], e = rowptr[n + 1];
    float acc = 0.f;
    for (int i = b; i < e; i++) {
        int s = colidx[i];
        acc += x[s * D + c];
    }
    agg[n * D + c] = acc * inv_deg[n];
}

// h = agg @ Wl^T + bl + x @ Wr^T ; also accumulate BN sum/sumsq per channel.
// block: 256 threads, tile of 64 nodes x 128 channels.
// thread t: channels j0=t&63 and j0+64; node group g=t>>6 (16 nodes each).
__global__ __launch_bounds__(256) void k_gemm(const float* __restrict__ agg, const float* __restrict__ xsrc,
                                              const float* __restrict__ Wl, const float* __restrict__ bl,
                                              const float* __restrict__ Wr, float* __restrict__ h,
                                              float* __restrict__ bnacc) {
    __shared__ float4 tile[64 * 32];  // 32KB
    const int t = threadIdx.x;
    const int j0 = t & 63;
    const int g = t >> 6;
    const int base = blockIdx.x * 64;

    float acc0[16], acc1[16];
#pragma unroll
    for (int k = 0; k < 16; k++) { acc0[k] = 0.f; acc1[k] = 0.f; }

    // ---- phase A: stage agg tile, multiply by Wl ----
    {
        const float4* A4 = (const float4*)agg;
#pragma unroll
        for (int i = 0; i < 8; i++) {
            int flat = i * 256 + t;
            int n_l = flat >> 5, c4 = flat & 31;
            int n = base + n_l;
            float4 v = make_float4(0.f, 0.f, 0.f, 0.f);
            if (n < N_NODES) v = A4[n * 32 + c4];
            tile[flat] = v;
        }
        __syncthreads();
        const float4* w0 = (const float4*)(Wl + j0 * D);
        const float4* w1 = (const float4*)(Wl + (j0 + 64) * D);
        for (int d4 = 0; d4 < 32; ++d4) {
            float4 wa = w0[d4], wb = w1[d4];
#pragma unroll
            for (int k = 0; k < 16; k++) {
                float4 a = tile[(g * 16 + k) * 32 + d4];
                acc0[k] = fmaf(a.x, wa.x, fmaf(a.y, wa.y, fmaf(a.z, wa.z, fmaf(a.w, wa.w, acc0[k]))));
                acc1[k] = fmaf(a.x, wb.x, fmaf(a.y, wb.y, fmaf(a.z, wb.z, fmaf(a.w, wb.w, acc1[k]))));
            }
        }
        __syncthreads();
    }
    // ---- phase B: stage x tile, multiply by Wr ----
    {
        const float4* X4 = (const float4*)xsrc;
#pragma unroll
        for (int i = 0; i < 8; i++) {
            int flat = i * 256 + t;
            int n_l = flat >> 5, c4 = flat & 31;
            int n = base + n_l;
            float4 v = make_float4(0.f, 0.f, 0.f, 0.f);
            if (n < N_NODES) v = X4[n * 32 + c4];
            tile[flat] = v;
        }
        __syncthreads();
        const float4* w0 = (const float4*)(Wr + j0 * D);
        const float4* w1 = (const float4*)(Wr + (j0 + 64) * D);
        for (int d4 = 0; d4 < 32; ++d4) {
            float4 wa = w0[d4], wb = w1[d4];
#pragma unroll
            for (int k = 0; k < 16; k++) {
                float4 a = tile[(g * 16 + k) * 32 + d4];
                acc0[k] = fmaf(a.x, wa.x, fmaf(a.y, wa.y, fmaf(a.z, wa.z, fmaf(a.w, wa.w, acc0[k]))));
                acc1[k] = fmaf(a.x, wb.x, fmaf(a.y, wb.y, fmaf(a.z, wb.z, fmaf(a.w, wb.w, acc1[k]))));
            }
        }
        __syncthreads();
    }

    // ---- epilogue: bias, write h, BN partials ----
    float b0 = bl[j0], b1 = bl[j0 + 64];
    float s10 = 0.f, s20 = 0.f, s11 = 0.f, s21 = 0.f;
#pragma unroll
    for (int k = 0; k < 16; k++) {
        int n = base + g * 16 + k;
        if (n < N_NODES) {
            float v0 = acc0[k] + b0;
            float v1 = acc1[k] + b1;
            h[n * D + j0] = v0;
            h[n * D + j0 + 64] = v1;
            s10 += v0; s20 += v0 * v0;
            s11 += v1; s21 += v1 * v1;
        }
    }
    float* red = (float*)tile;
    __syncthreads();
    red[t] = s10; __syncthreads();
    if (t < 64) { float v = red[t] + red[t + 64] + red[t + 128] + red[t + 192]; atomicAdd(&bnacc[t], v); }
    __syncthreads();
    red[t] = s20; __syncthreads();
    if (t < 64) { float v = red[t] + red[t + 64] + red[t + 128] + red[t + 192]; atomicAdd(&bnacc[128 + t], v); }
    __syncthreads();
    red[t] = s11; __syncthreads();
    if (t < 64) { float v = red[t] + red[t + 64] + red[t + 128] + red[t + 192]; atomicAdd(&bnacc[64 + t], v); }
    __syncthreads();
    red[t] = s21; __syncthreads();
    if (t < 64) { float v = red[t] + red[t + 64] + red[t + 128] + red[t + 192]; atomicAdd(&bnacc[192 + t], v); }
}

__global__ __launch_bounds__(128) void k_finalize(const float* __restrict__ bnacc, const float* __restrict__ gamma,
                                                  const float* __restrict__ beta, float* __restrict__ coef) {
    int j = threadIdx.x;
    float mean = bnacc[j] * (1.0f / N_NODES);
    float var = bnacc[128 + j] * (1.0f / N_NODES) - mean * mean;
    float inv = rsqrtf(var + BN_EPS);
    float a = gamma[j] * inv;
    coef[j] = a;
    coef[128 + j] = beta[j] - mean * a;
}

__global__ __launch_bounds__(256) void k_apply(const float* __restrict__ h, const float* __restrict__ coef,
                                               const float* __restrict__ xres, float* __restrict__ out, int use_res) {
    int idx = blockIdx.x * 256 + threadIdx.x;  // float4 index
    if (idx >= N_NODES * 32) return;
    int c4 = idx & 31;
    float4 hv = ((const float4*)h)[idx];
    float4 a = ((const float4*)coef)[c4];
    float4 c = ((const float4*)coef)[32 + c4];
    float4 r;
    r.x = fmaxf(fmaf(hv.x, a.x, c.x), 0.f);
    r.y = fmaxf(fmaf(hv.y, a.y, c.y), 0.f);
    r.z = fmaxf(fmaf(hv.z, a.z, c.z), 0.f);
    r.w = fmaxf(fmaf(hv.w, a.w, c.w), 0.f);
    if (use_res) {
        float4 xv = ((const float4*)xres)[idx];
        r.x = fmaf(0.5f, r.x, xv.x);
        r.y = fmaf(0.5f, r.y, xv.y);
        r.z = fmaf(0.5f, r.z, xv.z);
        r.w = fmaf(0.5f, r.w, xv.w);
    }
    ((float4*)out)[idx] = r;
}

// ---------------- launch ----------------

extern "C" void kernel_launch(void* const* d_in, const int* in_sizes, int n_in,
                              void* d_out, int out_size, void* d_ws, size_t ws_size,
                              hipStream_t stream) {
    const float* x_in = (const float*)d_in[0];
    const int* ei = (const int*)d_in[1];
    const float* Wl = (const float*)d_in[2];
    const float* bl = (const float*)d_in[3];
    const float* Wr = (const float*)d_in[4];
    const float* gamma = (const float*)d_in[5];
    const float* beta = (const float*)d_in[6];
    float* out = (float*)d_out;

    char* ws = (char*)d_ws;
    float* bufA = (float*)ws; ws += (size_t)N_NODES * D * 4;
    float* bufB = (float*)ws; ws += (size_t)N_NODES * D * 4;
    int* rowptr = (int*)ws; ws += (size_t)(N_NODES + 1) * 4;
    int* degi = (int*)ws; ws += (size_t)N_NODES * 4;
    int* cursor = (int*)ws; ws += (size_t)N_NODES * 4;
    int* colidx = (int*)ws; ws += (size_t)N_EDGES * 4;
    float* inv_deg = (float*)ws; ws += (size_t)N_NODES * 4;
    float* bnacc = (float*)ws; ws += 256 * 4;
    float* coef = (float*)ws; ws += 256 * 4;

    const int* src = ei;
    const int* dst = ei + N_EDGES;

    // CSR build (per call; deterministic up to f32 sum order)
    hipMemsetAsync(degi, 0, (size_t)N_NODES * 4, stream);
    hipMemsetAsync(cursor, 0, (size_t)N_NODES * 4, stream);
    k_deg<<<(N_EDGES + 255) / 256, 256, 0, stream>>>(dst, degi);
    k_scan<<<1, 1024, 0, stream>>>(degi, rowptr, inv_deg);
    k_fill<<<(N_EDGES + 255) / 256, 256, 0, stream>>>(src, dst, rowptr, cursor, colidx);

    // layer i: xin -> aggbuf -> h(d_out) -> xout
    const float* xin[3] = { x_in, bufB, bufA };
    float* aggbuf[3] = { bufA, bufA, bufB };
    float* xout[3] = { bufB, bufA, out };
    int use_res[3] = { 0, 1, 0 };

    for (int i = 0; i < 3; i++) {
        k_agg<<<N_NODES, 128, 0, stream>>>(xin[i], rowptr, colidx, inv_deg, aggbuf[i]);
        hipMemsetAsync(bnacc, 0, 256 * 4, stream);
        k_gemm<<<(N_NODES + 63) / 64, 256, 0, stream>>>(aggbuf[i], xin[i],
                                                        Wl + (size_t)i * D * D, bl + (size_t)i * D,
                                                        Wr + (size_t)i * D * D, out, bnacc);
        k_finalize<<<1, 128, 0, stream>>>(bnacc, gamma + (size_t)i * D, beta + (size_t)i * D, coef);
        k_apply<<<(N_NODES * 32 + 255) / 256, 256, 0, stream>>>(out, coef, xin[i], xout[i], use_res[i]);
    }
}

// Round 2
// 1273.935 us; speedup vs baseline: 1.1768x; 1.1768x over previous
//
#include <hip/hip_runtime.h>

#define N_NODES 100000
#define N_EDGES 1600000
#define D 128
#define BN_EPS 1e-5f
#define N_BLK ((N_NODES + 255) / 256)  // 391

// ---------------- CSR build ----------------

__global__ __launch_bounds__(256) void k_deg(const int* __restrict__ dst, int* __restrict__ degi) {
    int e = blockIdx.x * 256 + threadIdx.x;
    if (e < N_EDGES) atomicAdd(&degi[dst[e]], 1);
}

// hierarchical scan: block sums -> scan of sums -> per-block exclusive scan
__global__ __launch_bounds__(256) void k_blocksum(const int* __restrict__ degi, int* __restrict__ bsum) {
    __shared__ int sm[256];
    int t = threadIdx.x;
    int i = blockIdx.x * 256 + t;
    sm[t] = (i < N_NODES) ? degi[i] : 0;
    __syncthreads();
    for (int off = 128; off > 0; off >>= 1) {
        if (t < off) sm[t] += sm[t + off];
        __syncthreads();
    }
    if (t == 0) bsum[blockIdx.x] = sm[0];
}

__global__ __launch_bounds__(512) void k_scan_bsum(const int* __restrict__ bsum, int* __restrict__ boff) {
    __shared__ int sm[512];
    int t = threadIdx.x;
    int v = (t < N_BLK) ? bsum[t] : 0;
    sm[t] = v;
    __syncthreads();
    for (int off = 1; off < 512; off <<= 1) {
        int u = (t >= off) ? sm[t - off] : 0;
        __syncthreads();
        sm[t] += u;
        __syncthreads();
    }
    if (t < N_BLK) boff[t] = sm[t] - v;  // exclusive offset of block t
}

__global__ __launch_bounds__(256) void k_rowptr(const int* __restrict__ degi, const int* __restrict__ boff,
                                                int* __restrict__ rowptr, float* __restrict__ inv_deg) {
    __shared__ int sm[256];
    int t = threadIdx.x;
    int i = blockIdx.x * 256 + t;
    int v = (i < N_NODES) ? degi[i] : 0;
    sm[t] = v;
    __syncthreads();
    for (int off = 1; off < 256; off <<= 1) {
        int u = (t >= off) ? sm[t - off] : 0;
        __syncthreads();
        sm[t] += u;
        __syncthreads();
    }
    if (i < N_NODES) {
        int incl = sm[t] + boff[blockIdx.x];
        rowptr[i] = incl - v;
        inv_deg[i] = 1.0f / fmaxf((float)v, 1.0f);
        if (i == N_NODES - 1) rowptr[N_NODES] = incl;
    }
}

__global__ __launch_bounds__(256) void k_fill(const int* __restrict__ src, const int* __restrict__ dst,
                                              const int* __restrict__ rowptr, int* __restrict__ cursor,
                                              int* __restrict__ colidx) {
    int e = blockIdx.x * 256 + threadIdx.x;
    if (e < N_EDGES) {
        int d = dst[e];
        int pos = atomicAdd(&cursor[d], 1);
        colidx[rowptr[d] + pos] = src[e];
    }
}

// ---------------- per-layer kernels ----------------

// mean aggregation: one block per node, one thread per channel
__global__ __launch_bounds__(128) void k_agg(const float* __restrict__ x, const int* __restrict__ rowptr,
                                             const int* __restrict__ colidx, const float* __restrict__ inv_deg,
                                             float* __restrict__ agg) {
    int n = blockIdx.x;
    int c = threadIdx.x;
    int b = rowptr[n], e = rowptr[n + 1];
    float acc = 0.f;
    for (int i = b; i < e; i++) {
        int s = colidx[i];
        acc += x[s * D + c];
    }
    agg[n * D + c] = acc * inv_deg[n];
}

// h = agg @ Wl^T + bl + x @ Wr^T ; also accumulate BN sum/sumsq per channel.
__global__ __launch_bounds__(256) void k_gemm(const float* __restrict__ agg, const float* __restrict__ xsrc,
                                              const float* __restrict__ Wl, const float* __restrict__ bl,
                                              const float* __restrict__ Wr, float* __restrict__ h,
                                              float* __restrict__ bnacc) {
    __shared__ float4 tile[64 * 32];  // 32KB
    const int t = threadIdx.x;
    const int j0 = t & 63;
    const int g = t >> 6;
    const int base = blockIdx.x * 64;

    float acc0[16], acc1[16];
#pragma unroll
    for (int k = 0; k < 16; k++) { acc0[k] = 0.f; acc1[k] = 0.f; }

    // ---- phase A: stage agg tile, multiply by Wl ----
    {
        const float4* A4 = (const float4*)agg;
#pragma unroll
        for (int i = 0; i < 8; i++) {
            int flat = i * 256 + t;
            int n_l = flat >> 5, c4 = flat & 31;
            int n = base + n_l;
            float4 v = make_float4(0.f, 0.f, 0.f, 0.f);
            if (n < N_NODES) v = A4[n * 32 + c4];
            tile[flat] = v;
        }
        __syncthreads();
        const float4* w0 = (const float4*)(Wl + j0 * D);
        const float4* w1 = (const float4*)(Wl + (j0 + 64) * D);
        for (int d4 = 0; d4 < 32; ++d4) {
            float4 wa = w0[d4], wb = w1[d4];
#pragma unroll
            for (int k = 0; k < 16; k++) {
                float4 a = tile[(g * 16 + k) * 32 + d4];
                acc0[k] = fmaf(a.x, wa.x, fmaf(a.y, wa.y, fmaf(a.z, wa.z, fmaf(a.w, wa.w, acc0[k]))));
                acc1[k] = fmaf(a.x, wb.x, fmaf(a.y, wb.y, fmaf(a.z, wb.z, fmaf(a.w, wb.w, acc1[k]))));
            }
        }
        __syncthreads();
    }
    // ---- phase B: stage x tile, multiply by Wr ----
    {
        const float4* X4 = (const float4*)xsrc;
#pragma unroll
        for (int i = 0; i < 8; i++) {
            int flat = i * 256 + t;
            int n_l = flat >> 5, c4 = flat & 31;
            int n = base + n_l;
            float4 v = make_float4(0.f, 0.f, 0.f, 0.f);
            if (n < N_NODES) v = X4[n * 32 + c4];
            tile[flat] = v;
        }
        __syncthreads();
        const float4* w0 = (const float4*)(Wr + j0 * D);
        const float4* w1 = (const float4*)(Wr + (j0 + 64) * D);
        for (int d4 = 0; d4 < 32; ++d4) {
            float4 wa = w0[d4], wb = w1[d4];
#pragma unroll
            for (int k = 0; k < 16; k++) {
                float4 a = tile[(g * 16 + k) * 32 + d4];
                acc0[k] = fmaf(a.x, wa.x, fmaf(a.y, wa.y, fmaf(a.z, wa.z, fmaf(a.w, wa.w, acc0[k]))));
                acc1[k] = fmaf(a.x, wb.x, fmaf(a.y, wb.y, fmaf(a.z, wb.z, fmaf(a.w, wb.w, acc1[k]))));
            }
        }
        __syncthreads();
    }

    // ---- epilogue: bias, write h, BN partials ----
    float b0 = bl[j0], b1 = bl[j0 + 64];
    float s10 = 0.f, s20 = 0.f, s11 = 0.f, s21 = 0.f;
#pragma unroll
    for (int k = 0; k < 16; k++) {
        int n = base + g * 16 + k;
        if (n < N_NODES) {
            float v0 = acc0[k] + b0;
            float v1 = acc1[k] + b1;
            h[n * D + j0] = v0;
            h[n * D + j0 + 64] = v1;
            s10 += v0; s20 += v0 * v0;
            s11 += v1; s21 += v1 * v1;
        }
    }
    float* red = (float*)tile;
    __syncthreads();
    red[t] = s10; __syncthreads();
    if (t < 64) { float v = red[t] + red[t + 64] + red[t + 128] + red[t + 192]; atomicAdd(&bnacc[t], v); }
    __syncthreads();
    red[t] = s20; __syncthreads();
    if (t < 64) { float v = red[t] + red[t + 64] + red[t + 128] + red[t + 192]; atomicAdd(&bnacc[128 + t], v); }
    __syncthreads();
    red[t] = s11; __syncthreads();
    if (t < 64) { float v = red[t] + red[t + 64] + red[t + 128] + red[t + 192]; atomicAdd(&bnacc[64 + t], v); }
    __syncthreads();
    red[t] = s21; __syncthreads();
    if (t < 64) { float v = red[t] + red[t + 64] + red[t + 128] + red[t + 192]; atomicAdd(&bnacc[192 + t], v); }
}

__global__ __launch_bounds__(128) void k_finalize(const float* __restrict__ bnacc, const float* __restrict__ gamma,
                                                  const float* __restrict__ beta, float* __restrict__ coef) {
    int j = threadIdx.x;
    float mean = bnacc[j] * (1.0f / N_NODES);
    float var = bnacc[128 + j] * (1.0f / N_NODES) - mean * mean;
    float inv = rsqrtf(var + BN_EPS);
    float a = gamma[j] * inv;
    coef[j] = a;
    coef[128 + j] = beta[j] - mean * a;
}

__global__ __launch_bounds__(256) void k_apply(const float* __restrict__ h, const float* __restrict__ coef,
                                               const float* __restrict__ xres, float* __restrict__ out, int use_res) {
    int idx = blockIdx.x * 256 + threadIdx.x;  // float4 index
    if (idx >= N_NODES * 32) return;
    int c4 = idx & 31;
    float4 hv = ((const float4*)h)[idx];
    float4 a = ((const float4*)coef)[c4];
    float4 c = ((const float4*)coef)[32 + c4];
    float4 r;
    r.x = fmaxf(fmaf(hv.x, a.x, c.x), 0.f);
    r.y = fmaxf(fmaf(hv.y, a.y, c.y), 0.f);
    r.z = fmaxf(fmaf(hv.z, a.z, c.z), 0.f);
    r.w = fmaxf(fmaf(hv.w, a.w, c.w), 0.f);
    if (use_res) {
        float4 xv = ((const float4*)xres)[idx];
        r.x = fmaf(0.5f, r.x, xv.x);
        r.y = fmaf(0.5f, r.y, xv.y);
        r.z = fmaf(0.5f, r.z, xv.z);
        r.w = fmaf(0.5f, r.w, xv.w);
    }
    ((float4*)out)[idx] = r;
}

// ---------------- launch ----------------

extern "C" void kernel_launch(void* const* d_in, const int* in_sizes, int n_in,
                              void* d_out, int out_size, void* d_ws, size_t ws_size,
                              hipStream_t stream) {
    const float* x_in = (const float*)d_in[0];
    const int* ei = (const int*)d_in[1];
    const float* Wl = (const float*)d_in[2];
    const float* bl = (const float*)d_in[3];
    const float* Wr = (const float*)d_in[4];
    const float* gamma = (const float*)d_in[5];
    const float* beta = (const float*)d_in[6];
    float* out = (float*)d_out;

    char* ws = (char*)d_ws;
    float* bufA = (float*)ws; ws += (size_t)N_NODES * D * 4;
    float* bufB = (float*)ws; ws += (size_t)N_NODES * D * 4;
    int* rowptr = (int*)ws; ws += (size_t)(N_NODES + 1) * 4;
    int* degi = (int*)ws; ws += (size_t)N_NODES * 4;
    int* cursor = (int*)ws; ws += (size_t)N_NODES * 4;
    int* colidx = (int*)ws; ws += (size_t)N_EDGES * 4;
    float* inv_deg = (float*)ws; ws += (size_t)N_NODES * 4;
    int* bsum = (int*)ws; ws += (size_t)N_BLK * 4;
    int* boff = (int*)ws; ws += (size_t)N_BLK * 4;
    float* bnacc = (float*)ws; ws += 256 * 4;
    float* coef = (float*)ws; ws += 256 * 4;

    const int* src = ei;
    const int* dst = ei + N_EDGES;

    // CSR build (per call; deterministic up to f32 sum order)
    hipMemsetAsync(degi, 0, (size_t)N_NODES * 4, stream);
    hipMemsetAsync(cursor, 0, (size_t)N_NODES * 4, stream);
    k_deg<<<(N_EDGES + 255) / 256, 256, 0, stream>>>(dst, degi);
    k_blocksum<<<N_BLK, 256, 0, stream>>>(degi, bsum);
    k_scan_bsum<<<1, 512, 0, stream>>>(bsum, boff);
    k_rowptr<<<N_BLK, 256, 0, stream>>>(degi, boff, rowptr, inv_deg);
    k_fill<<<(N_EDGES + 255) / 256, 256, 0, stream>>>(src, dst, rowptr, cursor, colidx);

    // layer i: xin -> aggbuf -> h(d_out) -> xout
    const float* xin[3] = { x_in, bufB, bufA };
    float* aggbuf[3] = { bufA, bufA, bufB };
    float* xout[3] = { bufB, bufA, out };
    int use_res[3] = { 0, 1, 0 };

    for (int i = 0; i < 3; i++) {
        k_agg<<<N_NODES, 128, 0, stream>>>(xin[i], rowptr, colidx, inv_deg, aggbuf[i]);
        hipMemsetAsync(bnacc, 0, 256 * 4, stream);
        k_gemm<<<(N_NODES + 63) / 64, 256, 0, stream>>>(aggbuf[i], xin[i],
                                                        Wl + (size_t)i * D * D, bl + (size_t)i * D,
                                                        Wr + (size_t)i * D * D, out, bnacc);
        k_finalize<<<1, 128, 0, stream>>>(bnacc, gamma + (size_t)i * D, beta + (size_t)i * D, coef);
        k_apply<<<(N_NODES * 32 + 255) / 256, 256, 0, stream>>>(out, coef, xin[i], xout[i], use_res[i]);
    }
}

// Round 3
// 854.344 us; speedup vs baseline: 1.7548x; 1.4911x over previous
//
#include <hip/hip_runtime.h>

#define N_NODES 100000
#define N_EDGES 1600000
#define D 128
#define BN_EPS 1e-5f
#define N_BLK ((N_NODES + 255) / 256)  // 391

typedef short bf16x8 __attribute__((ext_vector_type(8)));
typedef float f32x4 __attribute__((ext_vector_type(4)));

__device__ inline unsigned short f32_to_bf16_rne(float f) {
    unsigned u = __builtin_bit_cast(unsigned, f);
    u += 0x7fffu + ((u >> 16) & 1u);
    return (unsigned short)(u >> 16);
}
__device__ inline float bf16lo_to_f32(unsigned v) {  // low 16 bits
    return __builtin_bit_cast(float, v << 16);
}
__device__ inline float bf16hi_to_f32(unsigned v) {  // high 16 bits
    return __builtin_bit_cast(float, v & 0xffff0000u);
}

// ---------------- CSR build ----------------

__global__ __launch_bounds__(256) void k_deg(const int* __restrict__ dst, int* __restrict__ degi) {
    int e = blockIdx.x * 256 + threadIdx.x;
    if (e < N_EDGES) atomicAdd(&degi[dst[e]], 1);
}

__global__ __launch_bounds__(256) void k_blocksum(const int* __restrict__ degi, int* __restrict__ bsum) {
    __shared__ int sm[256];
    int t = threadIdx.x;
    int i = blockIdx.x * 256 + t;
    sm[t] = (i < N_NODES) ? degi[i] : 0;
    __syncthreads();
    for (int off = 128; off > 0; off >>= 1) {
        if (t < off) sm[t] += sm[t + off];
        __syncthreads();
    }
    if (t == 0) bsum[blockIdx.x] = sm[0];
}

__global__ __launch_bounds__(512) void k_scan_bsum(const int* __restrict__ bsum, int* __restrict__ boff) {
    __shared__ int sm[512];
    int t = threadIdx.x;
    int v = (t < N_BLK) ? bsum[t] : 0;
    sm[t] = v;
    __syncthreads();
    for (int off = 1; off < 512; off <<= 1) {
        int u = (t >= off) ? sm[t - off] : 0;
        __syncthreads();
        sm[t] += u;
        __syncthreads();
    }
    if (t < N_BLK) boff[t] = sm[t] - v;
}

__global__ __launch_bounds__(256) void k_rowptr(const int* __restrict__ degi, const int* __restrict__ boff,
                                                int* __restrict__ rowptr, float* __restrict__ inv_deg) {
    __shared__ int sm[256];
    int t = threadIdx.x;
    int i = blockIdx.x * 256 + t;
    int v = (i < N_NODES) ? degi[i] : 0;
    sm[t] = v;
    __syncthreads();
    for (int off = 1; off < 256; off <<= 1) {
        int u = (t >= off) ? sm[t - off] : 0;
        __syncthreads();
        sm[t] += u;
        __syncthreads();
    }
    if (i < N_NODES) {
        int incl = sm[t] + boff[blockIdx.x];
        rowptr[i] = incl - v;
        inv_deg[i] = 1.0f / fmaxf((float)v, 1.0f);
        if (i == N_NODES - 1) rowptr[N_NODES] = incl;
    }
}

__global__ __launch_bounds__(256) void k_fill(const int* __restrict__ src, const int* __restrict__ dst,
                                              const int* __restrict__ rowptr, int* __restrict__ cursor,
                                              int* __restrict__ colidx) {
    int e = blockIdx.x * 256 + threadIdx.x;
    if (e < N_EDGES) {
        int d = dst[e];
        int pos = atomicAdd(&cursor[d], 1);
        colidx[rowptr[d] + pos] = src[e];
    }
}

// ---------------- conversions ----------------

// f32 [n] -> bf16 hi [n], float4 granularity (n multiple of 4)
__global__ __launch_bounds__(256) void k_xconv(const float* __restrict__ src, unsigned short* __restrict__ hi) {
    int idx = blockIdx.x * 256 + threadIdx.x;
    if (idx >= N_NODES * 32) return;
    float4 v = ((const float4*)src)[idx];
    uint2 p;
    p.x = (unsigned)f32_to_bf16_rne(v.x) | ((unsigned)f32_to_bf16_rne(v.y) << 16);
    p.y = (unsigned)f32_to_bf16_rne(v.z) | ((unsigned)f32_to_bf16_rne(v.w) << 16);
    ((uint2*)hi)[idx] = p;
}

// f32 [n] -> bf16 hi + bf16 lo (split precision), scalar
__global__ __launch_bounds__(256) void k_wconv(const float* __restrict__ src, unsigned short* __restrict__ hi,
                                               unsigned short* __restrict__ lo, int n) {
    int i = blockIdx.x * 256 + threadIdx.x;
    if (i >= n) return;
    float w = src[i];
    unsigned short h = f32_to_bf16_rne(w);
    float rem = w - bf16lo_to_f32((unsigned)h);
    hi[i] = h;
    lo[i] = f32_to_bf16_rne(rem);
}

// ---------------- per-layer kernels ----------------

// mean aggregation from bf16 x: one wave per node, lane handles 2 channels
__global__ __launch_bounds__(256) void k_agg(const unsigned short* __restrict__ xhi,
                                             const int* __restrict__ rowptr, const int* __restrict__ colidx,
                                             const float* __restrict__ inv_deg,
                                             unsigned short* __restrict__ agghi) {
    int wid = threadIdx.x >> 6;
    int l = threadIdx.x & 63;
    int n = blockIdx.x * 4 + wid;
    if (n >= N_NODES) return;
    int b = rowptr[n], e = rowptr[n + 1];
    float a0 = 0.f, a1 = 0.f;
    int i = b;
    for (; i + 4 <= e; i += 4) {
        int s0 = colidx[i], s1 = colidx[i + 1], s2 = colidx[i + 2], s3 = colidx[i + 3];
        unsigned v0 = *(const unsigned*)(xhi + (size_t)s0 * D + l * 2);
        unsigned v1 = *(const unsigned*)(xhi + (size_t)s1 * D + l * 2);
        unsigned v2 = *(const unsigned*)(xhi + (size_t)s2 * D + l * 2);
        unsigned v3 = *(const unsigned*)(xhi + (size_t)s3 * D + l * 2);
        a0 += bf16lo_to_f32(v0) + bf16lo_to_f32(v1) + bf16lo_to_f32(v2) + bf16lo_to_f32(v3);
        a1 += bf16hi_to_f32(v0) + bf16hi_to_f32(v1) + bf16hi_to_f32(v2) + bf16hi_to_f32(v3);
    }
    for (; i < e; ++i) {
        int s = colidx[i];
        unsigned v = *(const unsigned*)(xhi + (size_t)s * D + l * 2);
        a0 += bf16lo_to_f32(v);
        a1 += bf16hi_to_f32(v);
    }
    float idg = inv_deg[n];
    a0 *= idg; a1 *= idg;
    unsigned packed = (unsigned)f32_to_bf16_rne(a0) | ((unsigned)f32_to_bf16_rne(a1) << 16);
    *(unsigned*)(agghi + (size_t)n * D + l * 2) = packed;
}

// h = agg @ Wl^T + bl + x @ Wr^T via MFMA (data bf16-hi, W split hi+lo).
// 256 threads = 4 waves; tile 64 nodes x 128 cols; wave w: all 64 nodes x cols [w*32, w*32+32).
__global__ __launch_bounds__(256) void k_gemm(
    const unsigned short* __restrict__ agg_hi, const unsigned short* __restrict__ x_hi,
    const unsigned short* __restrict__ wl_hi, const unsigned short* __restrict__ wl_lo,
    const unsigned short* __restrict__ wr_hi, const unsigned short* __restrict__ wr_lo,
    const float* __restrict__ bl, float* __restrict__ h, float* __restrict__ bnacc) {
    const int t = threadIdx.x;
    const int w = t >> 6;
    const int l = t & 63;
    const int base = blockIdx.x * 64;
    const int j0 = w * 32;
    const int lr = l & 15;
    const int lg = l >> 4;

    f32x4 acc[4][2];
#pragma unroll
    for (int m = 0; m < 4; m++)
#pragma unroll
        for (int f = 0; f < 2; f++) acc[m][f] = (f32x4){0.f, 0.f, 0.f, 0.f};

    size_t aoff[4];
#pragma unroll
    for (int m = 0; m < 4; m++) {
        int n = base + m * 16 + lr;
        if (n > N_NODES - 1) n = N_NODES - 1;
        aoff[m] = (size_t)n * D;
    }

#pragma unroll
    for (int seg = 0; seg < 2; ++seg) {
        const unsigned short* A = seg ? x_hi : agg_hi;
        const unsigned short* WH = seg ? wr_hi : wl_hi;
        const unsigned short* WL = seg ? wr_lo : wl_lo;
#pragma unroll
        for (int kk = 0; kk < 4; ++kk) {
            const int ko = kk * 32 + lg * 8;
            bf16x8 a[4];
#pragma unroll
            for (int m = 0; m < 4; m++) a[m] = *(const bf16x8*)(A + aoff[m] + ko);
#pragma unroll
            for (int f = 0; f < 2; ++f) {
                const int wrow = (j0 + f * 16 + lr) * D + ko;
                bf16x8 bh = *(const bf16x8*)(WH + wrow);
                bf16x8 blo = *(const bf16x8*)(WL + wrow);
#pragma unroll
                for (int m = 0; m < 4; m++) {
                    acc[m][f] = __builtin_amdgcn_mfma_f32_16x16x32_bf16(a[m], bh, acc[m][f], 0, 0, 0);
                    acc[m][f] = __builtin_amdgcn_mfma_f32_16x16x32_bf16(a[m], blo, acc[m][f], 0, 0, 0);
                }
            }
        }
    }

    // epilogue: bias, store h, BN partial sums
    float s1[2] = {0.f, 0.f}, s2[2] = {0.f, 0.f};
#pragma unroll
    for (int f = 0; f < 2; ++f) {
        const int col = j0 + f * 16 + lr;
        const float bias = bl[col];
#pragma unroll
        for (int m = 0; m < 4; m++) {
#pragma unroll
            for (int r = 0; r < 4; r++) {
                int n = base + m * 16 + lg * 4 + r;
                if (n < N_NODES) {
                    float v = acc[m][f][r] + bias;
                    h[(size_t)n * D + col] = v;
                    s1[f] += v;
                    s2[f] += v * v;
                }
            }
        }
    }
#pragma unroll
    for (int f = 0; f < 2; ++f) {
        s1[f] += __shfl_xor(s1[f], 16);
        s1[f] += __shfl_xor(s1[f], 32);
        s2[f] += __shfl_xor(s2[f], 16);
        s2[f] += __shfl_xor(s2[f], 32);
    }
    if (l < 16) {
        atomicAdd(&bnacc[j0 + l], s1[0]);
        atomicAdd(&bnacc[j0 + 16 + l], s1[1]);
        atomicAdd(&bnacc[128 + j0 + l], s2[0]);
        atomicAdd(&bnacc[128 + j0 + 16 + l], s2[1]);
    }
}

__global__ __launch_bounds__(128) void k_finalize(const float* __restrict__ bnacc, const float* __restrict__ gamma,
                                                  const float* __restrict__ beta, float* __restrict__ coef) {
    int j = threadIdx.x;
    float mean = bnacc[j] * (1.0f / N_NODES);
    float var = bnacc[128 + j] * (1.0f / N_NODES) - mean * mean;
    float inv = rsqrtf(var + BN_EPS);
    float a = gamma[j] * inv;
    coef[j] = a;
    coef[128 + j] = beta[j] - mean * a;
}

// mode 0: out_hi = relu(bn(h)); mode 1: out_hi = xres + 0.5*relu(bn(h)); mode 2: out_f32 = relu(bn(h))
__global__ __launch_bounds__(256) void k_apply(const float* __restrict__ h, const float* __restrict__ coef,
                                               const unsigned short* __restrict__ xres_hi,
                                               unsigned short* __restrict__ out_hi,
                                               float* __restrict__ out_f32, int mode) {
    int idx = blockIdx.x * 256 + threadIdx.x;  // float4 group of 4 channels
    if (idx >= N_NODES * 32) return;
    int c4 = idx & 31;
    float4 hv = ((const float4*)h)[idx];
    float4 a = ((const float4*)coef)[c4];
    float4 c = ((const float4*)coef)[32 + c4];
    float4 r;
    r.x = fmaxf(fmaf(hv.x, a.x, c.x), 0.f);
    r.y = fmaxf(fmaf(hv.y, a.y, c.y), 0.f);
    r.z = fmaxf(fmaf(hv.z, a.z, c.z), 0.f);
    r.w = fmaxf(fmaf(hv.w, a.w, c.w), 0.f);
    if (mode == 1) {
        uint2 xv = ((const uint2*)xres_hi)[idx];
        r.x = fmaf(0.5f, r.x, bf16lo_to_f32(xv.x));
        r.y = fmaf(0.5f, r.y, bf16hi_to_f32(xv.x));
        r.z = fmaf(0.5f, r.z, bf16lo_to_f32(xv.y));
        r.w = fmaf(0.5f, r.w, bf16hi_to_f32(xv.y));
    }
    if (mode == 2) {
        ((float4*)out_f32)[idx] = r;
    } else {
        uint2 p;
        p.x = (unsigned)f32_to_bf16_rne(r.x) | ((unsigned)f32_to_bf16_rne(r.y) << 16);
        p.y = (unsigned)f32_to_bf16_rne(r.z) | ((unsigned)f32_to_bf16_rne(r.w) << 16);
        ((uint2*)out_hi)[idx] = p;
    }
}

// ---------------- launch ----------------

extern "C" void kernel_launch(void* const* d_in, const int* in_sizes, int n_in,
                              void* d_out, int out_size, void* d_ws, size_t ws_size,
                              hipStream_t stream) {
    const float* x_in = (const float*)d_in[0];
    const int* ei = (const int*)d_in[1];
    const float* Wl = (const float*)d_in[2];
    const float* bl = (const float*)d_in[3];
    const float* Wr = (const float*)d_in[4];
    const float* gamma = (const float*)d_in[5];
    const float* beta = (const float*)d_in[6];
    float* out = (float*)d_out;

    char* ws = (char*)d_ws;
    unsigned short* xhiA = (unsigned short*)ws; ws += (size_t)N_NODES * D * 2;
    unsigned short* xhiB = (unsigned short*)ws; ws += (size_t)N_NODES * D * 2;
    unsigned short* agghi = (unsigned short*)ws; ws += (size_t)N_NODES * D * 2;
    int* rowptr = (int*)ws; ws += (size_t)(N_NODES + 1) * 4;
    int* degi = (int*)ws; ws += (size_t)N_NODES * 4;
    int* cursor = (int*)ws; ws += (size_t)N_NODES * 4;
    int* colidx = (int*)ws; ws += (size_t)N_EDGES * 4;
    float* inv_deg = (float*)ws; ws += (size_t)N_NODES * 4;
    int* bsum = (int*)ws; ws += (size_t)N_BLK * 4;
    int* boff = (int*)ws; ws += (size_t)N_BLK * 4;
    unsigned short* wl_hi = (unsigned short*)ws; ws += (size_t)3 * D * D * 2;
    unsigned short* wl_lo = (unsigned short*)ws; ws += (size_t)3 * D * D * 2;
    unsigned short* wr_hi = (unsigned short*)ws; ws += (size_t)3 * D * D * 2;
    unsigned short* wr_lo = (unsigned short*)ws; ws += (size_t)3 * D * D * 2;
    float* bnacc = (float*)ws; ws += 256 * 4;
    float* coef = (float*)ws; ws += 256 * 4;

    const int* src = ei;
    const int* dst = ei + N_EDGES;

    // CSR build
    hipMemsetAsync(degi, 0, (size_t)N_NODES * 4, stream);
    hipMemsetAsync(cursor, 0, (size_t)N_NODES * 4, stream);
    k_deg<<<(N_EDGES + 255) / 256, 256, 0, stream>>>(dst, degi);
    k_blocksum<<<N_BLK, 256, 0, stream>>>(degi, bsum);
    k_scan_bsum<<<1, 512, 0, stream>>>(bsum, boff);
    k_rowptr<<<N_BLK, 256, 0, stream>>>(degi, boff, rowptr, inv_deg);
    k_fill<<<(N_EDGES + 255) / 256, 256, 0, stream>>>(src, dst, rowptr, cursor, colidx);

    // conversions
    k_xconv<<<(N_NODES * 32 + 255) / 256, 256, 0, stream>>>(x_in, xhiA);
    k_wconv<<<(3 * D * D + 255) / 256, 256, 0, stream>>>(Wl, wl_hi, wl_lo, 3 * D * D);
    k_wconv<<<(3 * D * D + 255) / 256, 256, 0, stream>>>(Wr, wr_hi, wr_lo, 3 * D * D);

    unsigned short* xin[3] = { xhiA, xhiB, xhiA };
    unsigned short* xout[3] = { xhiB, xhiA, (unsigned short*)0 };
    int mode[3] = { 0, 1, 2 };
    float* hbuf = out;  // d_out doubles as h scratch

    for (int i = 0; i < 3; i++) {
        k_agg<<<(N_NODES + 3) / 4, 256, 0, stream>>>(xin[i], rowptr, colidx, inv_deg, agghi);
        hipMemsetAsync(bnacc, 0, 256 * 4, stream);
        k_gemm<<<(N_NODES + 63) / 64, 256, 0, stream>>>(agghi, xin[i],
                                                        wl_hi + (size_t)i * D * D, wl_lo + (size_t)i * D * D,
                                                        wr_hi + (size_t)i * D * D, wr_lo + (size_t)i * D * D,
                                                        bl + (size_t)i * D, hbuf, bnacc);
        k_finalize<<<1, 128, 0, stream>>>(bnacc, gamma + (size_t)i * D, beta + (size_t)i * D, coef);
        k_apply<<<(N_NODES * 32 + 255) / 256, 256, 0, stream>>>(hbuf, coef, xin[i], xout[i], out, mode[i]);
    }
}

// Round 4
// 771.488 us; speedup vs baseline: 1.9432x; 1.1074x over previous
//
#include <hip/hip_runtime.h>

#define N_NODES 100000
#define N_EDGES 1600000
#define D 128
#define BN_EPS 1e-5f
#define N_BLK ((N_NODES + 255) / 256)  // 391

typedef short bf16x8 __attribute__((ext_vector_type(8)));
typedef float f32x4 __attribute__((ext_vector_type(4)));

__device__ inline unsigned short f32_to_bf16_rne(float f) {
    unsigned u = __builtin_bit_cast(unsigned, f);
    u += 0x7fffu + ((u >> 16) & 1u);
    return (unsigned short)(u >> 16);
}
__device__ inline float bf16lo_to_f32(unsigned v) { return __builtin_bit_cast(float, v << 16); }
__device__ inline float bf16hi_to_f32(unsigned v) { return __builtin_bit_cast(float, v & 0xffff0000u); }

__device__ inline void gload_lds16(const void* g, void* l) {
    __builtin_amdgcn_global_load_lds((const __attribute__((address_space(1))) unsigned*)g,
                                     (__attribute__((address_space(3))) unsigned*)l, 16, 0, 0);
}

// ---------------- CSR build ----------------

__global__ __launch_bounds__(256) void k_deg(const int* __restrict__ dst, int* __restrict__ degi) {
    int e = blockIdx.x * 256 + threadIdx.x;
    if (e < N_EDGES) atomicAdd(&degi[dst[e]], 1);
}

__global__ __launch_bounds__(256) void k_blocksum(const int* __restrict__ degi, int* __restrict__ bsum) {
    __shared__ int sm[256];
    int t = threadIdx.x;
    int i = blockIdx.x * 256 + t;
    sm[t] = (i < N_NODES) ? degi[i] : 0;
    __syncthreads();
    for (int off = 128; off > 0; off >>= 1) {
        if (t < off) sm[t] += sm[t + off];
        __syncthreads();
    }
    if (t == 0) bsum[blockIdx.x] = sm[0];
}

__global__ __launch_bounds__(512) void k_scan_bsum(const int* __restrict__ bsum, int* __restrict__ boff) {
    __shared__ int sm[512];
    int t = threadIdx.x;
    int v = (t < N_BLK) ? bsum[t] : 0;
    sm[t] = v;
    __syncthreads();
    for (int off = 1; off < 512; off <<= 1) {
        int u = (t >= off) ? sm[t - off] : 0;
        __syncthreads();
        sm[t] += u;
        __syncthreads();
    }
    if (t < N_BLK) boff[t] = sm[t] - v;
}

__global__ __launch_bounds__(256) void k_rowptr(const int* __restrict__ degi, const int* __restrict__ boff,
                                                int* __restrict__ rowptr, float* __restrict__ inv_deg) {
    __shared__ int sm[256];
    int t = threadIdx.x;
    int i = blockIdx.x * 256 + t;
    int v = (i < N_NODES) ? degi[i] : 0;
    sm[t] = v;
    __syncthreads();
    for (int off = 1; off < 256; off <<= 1) {
        int u = (t >= off) ? sm[t - off] : 0;
        __syncthreads();
        sm[t] += u;
        __syncthreads();
    }
    if (i < N_NODES) {
        int incl = sm[t] + boff[blockIdx.x];
        rowptr[i] = incl - v;
        inv_deg[i] = 1.0f / fmaxf((float)v, 1.0f);
        if (i == N_NODES - 1) rowptr[N_NODES] = incl;
    }
}

__global__ __launch_bounds__(256) void k_fill(const int* __restrict__ src, const int* __restrict__ dst,
                                              const int* __restrict__ rowptr, int* __restrict__ cursor,
                                              int* __restrict__ colidx) {
    int e = blockIdx.x * 256 + threadIdx.x;
    if (e < N_EDGES) {
        int d = dst[e];
        int pos = atomicAdd(&cursor[d], 1);
        colidx[rowptr[d] + pos] = src[e];
    }
}

// ---------------- conversions ----------------

__global__ __launch_bounds__(256) void k_xconv(const float* __restrict__ src, unsigned short* __restrict__ hi) {
    int idx = blockIdx.x * 256 + threadIdx.x;
    if (idx >= N_NODES * 32) return;
    float4 v = ((const float4*)src)[idx];
    uint2 p;
    p.x = (unsigned)f32_to_bf16_rne(v.x) | ((unsigned)f32_to_bf16_rne(v.y) << 16);
    p.y = (unsigned)f32_to_bf16_rne(v.z) | ((unsigned)f32_to_bf16_rne(v.w) << 16);
    ((uint2*)hi)[idx] = p;
}

__global__ __launch_bounds__(256) void k_wconv(const float* __restrict__ src, unsigned short* __restrict__ hi,
                                               unsigned short* __restrict__ lo, int n) {
    int i = blockIdx.x * 256 + threadIdx.x;
    if (i >= n) return;
    float w = src[i];
    unsigned short h = f32_to_bf16_rne(w);
    float rem = w - bf16lo_to_f32((unsigned)h);
    hi[i] = h;
    lo[i] = f32_to_bf16_rne(rem);
}

// ---------------- per-layer kernels ----------------

// mean aggregation: one wave per node, 2 edges per load-step (32 lanes x 8B each)
__global__ __launch_bounds__(256) void k_agg(const unsigned short* __restrict__ xhi,
                                             const int* __restrict__ rowptr, const int* __restrict__ colidx,
                                             const float* __restrict__ inv_deg,
                                             unsigned short* __restrict__ agghi) {
    int wid = threadIdx.x >> 6;
    int l = threadIdx.x & 63;
    int n = blockIdx.x * 4 + wid;
    if (n >= N_NODES) return;
    int b = rowptr[n], e = rowptr[n + 1];
    const int half = l >> 5;
    const int cl = l & 31;  // 4-channel group
    float a0 = 0.f, a1 = 0.f, a2 = 0.f, a3 = 0.f;
    int i = b;
    for (; i + 8 <= e; i += 8) {
#pragma unroll
        for (int u = 0; u < 4; u++) {
            int s = colidx[i + u * 2 + half];
            uint2 v = *(const uint2*)(xhi + (size_t)s * D + cl * 4);
            a0 += bf16lo_to_f32(v.x); a1 += bf16hi_to_f32(v.x);
            a2 += bf16lo_to_f32(v.y); a3 += bf16hi_to_f32(v.y);
        }
    }
    for (; i + 2 <= e; i += 2) {
        int s = colidx[i + half];
        uint2 v = *(const uint2*)(xhi + (size_t)s * D + cl * 4);
        a0 += bf16lo_to_f32(v.x); a1 += bf16hi_to_f32(v.x);
        a2 += bf16lo_to_f32(v.y); a3 += bf16hi_to_f32(v.y);
    }
    if (i < e && half == 0) {
        int s = colidx[i];
        uint2 v = *(const uint2*)(xhi + (size_t)s * D + cl * 4);
        a0 += bf16lo_to_f32(v.x); a1 += bf16hi_to_f32(v.x);
        a2 += bf16lo_to_f32(v.y); a3 += bf16hi_to_f32(v.y);
    }
    a0 += __shfl_xor(a0, 32);
    a1 += __shfl_xor(a1, 32);
    a2 += __shfl_xor(a2, 32);
    a3 += __shfl_xor(a3, 32);
    if (half == 0) {
        float idg = inv_deg[n];
        uint2 p;
        p.x = (unsigned)f32_to_bf16_rne(a0 * idg) | ((unsigned)f32_to_bf16_rne(a1 * idg) << 16);
        p.y = (unsigned)f32_to_bf16_rne(a2 * idg) | ((unsigned)f32_to_bf16_rne(a3 * idg) << 16);
        *(uint2*)(agghi + (size_t)n * D + cl * 4) = p;
    }
}

// h(bf16) = agg @ Wl^T + bl + x @ Wr^T via MFMA; LDS-staged A tiles (XOR-swizzled),
// per-seg register-preloaded W frags (hi+lo split). BN partials to bnacc.
// NOTE: h may alias agg_hi (block stages its agg rows to LDS before overwriting).
__global__ __launch_bounds__(256) void k_gemm(
    const unsigned short* __restrict__ agg_hi, const unsigned short* __restrict__ x_hi,
    const unsigned short* __restrict__ wl_hi, const unsigned short* __restrict__ wl_lo,
    const unsigned short* __restrict__ wr_hi, const unsigned short* __restrict__ wr_lo,
    const float* __restrict__ bl, unsigned short* __restrict__ h, float* __restrict__ bnacc) {
    __shared__ char lds[32768];  // [0..16K): agg tile, [16K..32K): x tile; 64 rows x 256B, XOR-swizzled
    const int t = threadIdx.x;
    const int w = t >> 6;
    const int l = t & 63;
    const int lr = l & 15;
    const int lg = l >> 4;
    const int base = blockIdx.x * 64;
    const int j0 = w * 32;

    // ---- stage both tiles: wave w stages chunks [w*4, w*4+4) of each (chunk = 1KB = 4 rows) ----
    {
        int colb_l = lr * 16;
#pragma unroll
        for (int i = 0; i < 4; i++) {
            int cc = w * 4 + i;
            int row = cc * 4 + lg;
            int n = base + row;
            if (n > N_NODES - 1) n = N_NODES - 1;
            int colb = colb_l ^ ((row & 7) << 4);  // pre-swizzled source -> swizzled linear LDS
            size_t goff = (size_t)n * 256 + colb;
            gload_lds16((const char*)agg_hi + goff, lds + cc * 1024);
            gload_lds16((const char*)x_hi + goff, lds + 16384 + cc * 1024);
        }
    }

    f32x4 acc[4][2];
#pragma unroll
    for (int m = 0; m < 4; m++)
#pragma unroll
        for (int f = 0; f < 2; f++) acc[m][f] = (f32x4){0.f, 0.f, 0.f, 0.f};

#pragma unroll
    for (int seg = 0; seg < 2; seg++) {
        const unsigned short* WH = seg ? wr_hi : wl_hi;
        const unsigned short* WLo = seg ? wr_lo : wl_lo;
        bf16x8 wh[4][2], wlo[4][2];
#pragma unroll
        for (int kk = 0; kk < 4; kk++)
#pragma unroll
            for (int f = 0; f < 2; f++) {
                size_t wo = (size_t)(j0 + f * 16 + lr) * D + kk * 32 + lg * 8;
                wh[kk][f] = *(const bf16x8*)(WH + wo);
                wlo[kk][f] = *(const bf16x8*)(WLo + wo);
            }
        if (seg == 0) __syncthreads();  // drain global_load_lds (compiler emits vmcnt(0) before barrier)
        const int tb = seg * 16384;
#pragma unroll
        for (int kk = 0; kk < 4; kk++) {
            bf16x8 a[4];
#pragma unroll
            for (int m = 0; m < 4; m++) {
                int row = m * 16 + lr;
                int off = tb + row * 256 + ((kk * 64 + lg * 16) ^ ((lr & 7) << 4));
                a[m] = *(const bf16x8*)(lds + off);
            }
#pragma unroll
            for (int f = 0; f < 2; f++)
#pragma unroll
                for (int m = 0; m < 4; m++) {
                    acc[m][f] = __builtin_amdgcn_mfma_f32_16x16x32_bf16(a[m], wh[kk][f], acc[m][f], 0, 0, 0);
                    acc[m][f] = __builtin_amdgcn_mfma_f32_16x16x32_bf16(a[m], wlo[kk][f], acc[m][f], 0, 0, 0);
                }
        }
    }

    // ---- epilogue: bias, bf16 h store, BN partials ----
    float s1[2] = {0.f, 0.f}, s2[2] = {0.f, 0.f};
#pragma unroll
    for (int f = 0; f < 2; f++) {
        const int col = j0 + f * 16 + lr;
        const float bias = bl[col];
#pragma unroll
        for (int m = 0; m < 4; m++) {
#pragma unroll
            for (int r = 0; r < 4; r++) {
                int n = base + m * 16 + lg * 4 + r;
                if (n < N_NODES) {
                    float v = acc[m][f][r] + bias;
                    h[(size_t)n * D + col] = f32_to_bf16_rne(v);
                    s1[f] += v;
                    s2[f] += v * v;
                }
            }
        }
    }
#pragma unroll
    for (int f = 0; f < 2; f++) {
        s1[f] += __shfl_xor(s1[f], 16);
        s1[f] += __shfl_xor(s1[f], 32);
        s2[f] += __shfl_xor(s2[f], 16);
        s2[f] += __shfl_xor(s2[f], 32);
    }
    if (l < 16) {
        atomicAdd(&bnacc[j0 + l], s1[0]);
        atomicAdd(&bnacc[j0 + 16 + l], s1[1]);
        atomicAdd(&bnacc[128 + j0 + l], s2[0]);
        atomicAdd(&bnacc[128 + j0 + 16 + l], s2[1]);
    }
}

// BN-apply + ReLU (+residual); coef computed per-block from bnacc (fused finalize).
// mode 0: out_hi = relu(bn(h)); mode 1: out_hi = xres + 0.5*relu(bn(h)); mode 2: out_f32 = relu(bn(h))
__global__ __launch_bounds__(256) void k_apply(const unsigned short* __restrict__ h,
                                               const float* __restrict__ bnacc,
                                               const float* __restrict__ gamma, const float* __restrict__ beta,
                                               const unsigned short* __restrict__ xres_hi,
                                               unsigned short* __restrict__ out_hi,
                                               float* __restrict__ out_f32, int mode) {
    __shared__ float sa[128], sc[128];
    int t = threadIdx.x;
    if (t < 128) {
        float mean = bnacc[t] * (1.0f / N_NODES);
        float var = bnacc[128 + t] * (1.0f / N_NODES) - mean * mean;
        float inv = rsqrtf(var + BN_EPS);
        float av = gamma[t] * inv;
        sa[t] = av;
        sc[t] = beta[t] - mean * av;
    }
    __syncthreads();
    int idx = blockIdx.x * 256 + t;  // 4-channel group (8B bf16 / 16B f32)
    if (idx >= N_NODES * 32) return;
    int c0 = (idx & 31) * 4;
    uint2 hv = ((const uint2*)h)[idx];
    float r0 = fmaxf(fmaf(bf16lo_to_f32(hv.x), sa[c0], sc[c0]), 0.f);
    float r1 = fmaxf(fmaf(bf16hi_to_f32(hv.x), sa[c0 + 1], sc[c0 + 1]), 0.f);
    float r2 = fmaxf(fmaf(bf16lo_to_f32(hv.y), sa[c0 + 2], sc[c0 + 2]), 0.f);
    float r3 = fmaxf(fmaf(bf16hi_to_f32(hv.y), sa[c0 + 3], sc[c0 + 3]), 0.f);
    if (mode == 1) {
        uint2 xv = ((const uint2*)xres_hi)[idx];
        r0 = fmaf(0.5f, r0, bf16lo_to_f32(xv.x));
        r1 = fmaf(0.5f, r1, bf16hi_to_f32(xv.x));
        r2 = fmaf(0.5f, r2, bf16lo_to_f32(xv.y));
        r3 = fmaf(0.5f, r3, bf16hi_to_f32(xv.y));
    }
    if (mode == 2) {
        ((float4*)out_f32)[idx] = make_float4(r0, r1, r2, r3);
    } else {
        uint2 p;
        p.x = (unsigned)f32_to_bf16_rne(r0) | ((unsigned)f32_to_bf16_rne(r1) << 16);
        p.y = (unsigned)f32_to_bf16_rne(r2) | ((unsigned)f32_to_bf16_rne(r3) << 16);
        ((uint2*)out_hi)[idx] = p;
    }
}

// ---------------- launch ----------------

extern "C" void kernel_launch(void* const* d_in, const int* in_sizes, int n_in,
                              void* d_out, int out_size, void* d_ws, size_t ws_size,
                              hipStream_t stream) {
    const float* x_in = (const float*)d_in[0];
    const int* ei = (const int*)d_in[1];
    const float* Wl = (const float*)d_in[2];
    const float* bl = (const float*)d_in[3];
    const float* Wr = (const float*)d_in[4];
    const float* gamma = (const float*)d_in[5];
    const float* beta = (const float*)d_in[6];
    float* out = (float*)d_out;

    char* ws = (char*)d_ws;
    unsigned short* xhiA = (unsigned short*)ws; ws += (size_t)N_NODES * D * 2;
    unsigned short* xhiB = (unsigned short*)ws; ws += (size_t)N_NODES * D * 2;
    unsigned short* agghi = (unsigned short*)ws; ws += (size_t)N_NODES * D * 2;  // also h (aliased, safe)
    int* rowptr = (int*)ws; ws += (size_t)(N_NODES + 1) * 4;
    int* degi = (int*)ws; ws += (size_t)N_NODES * 4;
    int* cursor = (int*)ws; ws += (size_t)N_NODES * 4;
    int* colidx = (int*)ws; ws += (size_t)N_EDGES * 4;
    float* inv_deg = (float*)ws; ws += (size_t)N_NODES * 4;
    int* bsum = (int*)ws; ws += (size_t)N_BLK * 4;
    int* boff = (int*)ws; ws += (size_t)N_BLK * 4;
    unsigned short* wl_hi = (unsigned short*)ws; ws += (size_t)3 * D * D * 2;
    unsigned short* wl_lo = (unsigned short*)ws; ws += (size_t)3 * D * D * 2;
    unsigned short* wr_hi = (unsigned short*)ws; ws += (size_t)3 * D * D * 2;
    unsigned short* wr_lo = (unsigned short*)ws; ws += (size_t)3 * D * D * 2;
    float* bnacc = (float*)ws; ws += 256 * 4;

    const int* src = ei;
    const int* dst = ei + N_EDGES;

    // CSR build
    hipMemsetAsync(degi, 0, (size_t)N_NODES * 4, stream);
    hipMemsetAsync(cursor, 0, (size_t)N_NODES * 4, stream);
    k_deg<<<(N_EDGES + 255) / 256, 256, 0, stream>>>(dst, degi);
    k_blocksum<<<N_BLK, 256, 0, stream>>>(degi, bsum);
    k_scan_bsum<<<1, 512, 0, stream>>>(bsum, boff);
    k_rowptr<<<N_BLK, 256, 0, stream>>>(degi, boff, rowptr, inv_deg);
    k_fill<<<(N_EDGES + 255) / 256, 256, 0, stream>>>(src, dst, rowptr, cursor, colidx);

    // conversions
    k_xconv<<<(N_NODES * 32 + 255) / 256, 256, 0, stream>>>(x_in, xhiA);
    k_wconv<<<(3 * D * D + 255) / 256, 256, 0, stream>>>(Wl, wl_hi, wl_lo, 3 * D * D);
    k_wconv<<<(3 * D * D + 255) / 256, 256, 0, stream>>>(Wr, wr_hi, wr_lo, 3 * D * D);

    unsigned short* xin[3] = { xhiA, xhiB, xhiA };
    unsigned short* xout[3] = { xhiB, xhiA, (unsigned short*)0 };
    int mode[3] = { 0, 1, 2 };

    for (int i = 0; i < 3; i++) {
        k_agg<<<(N_NODES + 3) / 4, 256, 0, stream>>>(xin[i], rowptr, colidx, inv_deg, agghi);
        hipMemsetAsync(bnacc, 0, 256 * 4, stream);
        k_gemm<<<(N_NODES + 63) / 64, 256, 0, stream>>>(agghi, xin[i],
                                                        wl_hi + (size_t)i * D * D, wl_lo + (size_t)i * D * D,
                                                        wr_hi + (size_t)i * D * D, wr_lo + (size_t)i * D * D,
                                                        bl + (size_t)i * D, agghi, bnacc);
        k_apply<<<(N_NODES * 32 + 255) / 256, 256, 0, stream>>>(agghi, bnacc,
                                                                gamma + (size_t)i * D, beta + (size_t)i * D,
                                                                xin[i], xout[i], out, mode[i]);
    }
}